// Round 1
// baseline (988.531 us; speedup 1.0000x reference)
//
#include <hip/hip_runtime.h>
#include <hip/hip_bf16.h>
#include <cstdint>

#define HW 256
#define CH 64

__device__ __forceinline__ float b2f(unsigned short u) {
    union { unsigned int i; float f; } c; c.i = ((unsigned int)u) << 16; return c.f;
}

// ---------------------------------------------------------------------------
// Kernel W: reorder conv_w [co][ci][ky][kx] f32 -> wt[ky][ci][kx][co] bf16
// ---------------------------------------------------------------------------
__global__ void wt_kernel(const float* __restrict__ cw, __hip_bfloat16* __restrict__ wt) {
    int i = blockIdx.x * 256 + threadIdx.x;
    if (i >= 64 * 64 * 9) return;
    int co = i & 63;
    int r = i >> 6;          // (ky*64+ci)*3 + kx
    int kx = r % 3; r /= 3;  // ky*64 + ci
    int ci = r & 63;
    int ky = r >> 6;
    float v = cw[co * 576 + ci * 9 + ky * 3 + kx];
    wt[i] = __float2bfloat16(v);
}

// ---------------------------------------------------------------------------
// Kernel A: fused offset conv (fp32) + tanh + bilinear warp -> warped (bf16)
// block 16x16 threads = one 16x16 pixel tile; grid (16,16,B)
// ---------------------------------------------------------------------------
__global__ __launch_bounds__(256) void offset_warp_kernel(
    const float* __restrict__ x, const float* __restrict__ ow,
    const float* __restrict__ ob, __hip_bfloat16* __restrict__ warped)
{
    const int b = blockIdx.z;
    const int tx = threadIdx.x, ty = threadIdx.y;
    const int t = ty * 16 + tx;
    const int x0 = blockIdx.x * 16, y0 = blockIdx.y * 16;
    const int px = x0 + tx, py = y0 + ty;

    __shared__ float swt[2 * CH * 9];   // offset conv weights
    __shared__ float sxt[18][19];       // input tile + halo (padded stride)

    for (int i = t; i < 2 * CH * 9; i += 256) swt[i] = ow[i];

    float acc0 = ob[0], acc1 = ob[1];
    const float* xb = x + (size_t)b * CH * HW * HW;

    for (int ci = 0; ci < CH; ++ci) {
        __syncthreads();
        const float* xc = xb + (size_t)ci * HW * HW;
        for (int i = t; i < 18 * 18; i += 256) {
            int ly = i / 18, lx = i % 18;
            int gy = y0 + ly - 1, gx = x0 + lx - 1;
            float v = 0.f;
            if (gy >= 0 && gy < HW && gx >= 0 && gx < HW) v = xc[gy * HW + gx];
            sxt[ly][lx] = v;
        }
        __syncthreads();
        const float* w0 = &swt[ci * 9];
        const float* w1 = &swt[(CH + ci) * 9];
        #pragma unroll
        for (int ky = 0; ky < 3; ++ky) {
            #pragma unroll
            for (int kx = 0; kx < 3; ++kx) {
                float v = sxt[ty + ky][tx + kx];
                acc0 = fmaf(v, w0[ky * 3 + kx], acc0);
                acc1 = fmaf(v, w1[ky * 3 + kx], acc1);
            }
        }
    }

    float off0 = tanhf(acc0) * 2.0f;
    float off1 = tanhf(acc1) * 2.0f;
    // grid-sample position in pixel units (derivation: ix = x + off0, clamped)
    float ix = fminf(fmaxf((float)px + off0, 0.f), (float)(HW - 1));
    float iy = fminf(fmaxf((float)py + off1, 0.f), (float)(HW - 1));
    float fx0 = floorf(ix), fy0 = floorf(iy);
    float wx = ix - fx0, wy = iy - fy0;
    int x0i = (int)fx0, y0i = (int)fy0;
    int x1i = min(x0i + 1, HW - 1), y1i = min(y0i + 1, HW - 1);
    float w00 = (1.f - wx) * (1.f - wy), w01 = wx * (1.f - wy);
    float w10 = (1.f - wx) * wy,         w11 = wx * wy;

    int i00 = y0i * HW + x0i, i01 = y0i * HW + x1i;
    int i10 = y1i * HW + x0i, i11 = y1i * HW + x1i;
    __hip_bfloat16* wbuf = warped + (size_t)b * CH * HW * HW;
    size_t opix = (size_t)py * HW + px;
    for (int ci = 0; ci < CH; ++ci) {
        const float* xc = xb + (size_t)ci * HW * HW;
        float v = xc[i00] * w00 + xc[i01] * w01 + xc[i10] * w10 + xc[i11] * w11;
        wbuf[(size_t)ci * (HW * HW) + opix] = __float2bfloat16(v);
    }
}

// ---------------------------------------------------------------------------
// Kernel B: dilated(12) 3x3 conv 64->64 + BN + ReLU
// block = 256 threads: 64 co x 64 px tile (one output row segment), 4x4 micro-tile
// grid (4, 256, B)
// ---------------------------------------------------------------------------
__global__ __launch_bounds__(256, 2) void conv_bn_relu_kernel(
    const __hip_bfloat16* __restrict__ warped, const __hip_bfloat16* __restrict__ wt,
    const float* __restrict__ gamma, const float* __restrict__ beta,
    const float* __restrict__ mean, const float* __restrict__ var,
    float* __restrict__ out)
{
    __shared__ unsigned short sa[3][CH][88];     // [ky][ci][x] activations, 33.8 KB
    __shared__ unsigned short swm[CH * 3 * 64];  // [ci][kx][co] weights (one ky), 24.6 KB
    __shared__ float sinv[64], sbias[64];

    const int t = threadIdx.x;
    const int b = blockIdx.z, oy = blockIdx.y, ox0 = blockIdx.x * 64;

    if (t < 64) {
        float inv = gamma[t] * rsqrtf(var[t] + 1e-5f);
        sinv[t] = inv;
        sbias[t] = beta[t] - mean[t] * inv;
    }

    // stage 3 activation rows (with zero padding)
    const unsigned short* wb = (const unsigned short*)(warped + (size_t)b * CH * HW * HW);
    #pragma unroll
    for (int ky = 0; ky < 3; ++ky) {
        int gy = oy + (ky - 1) * 12;
        bool rowok = (gy >= 0) && (gy < HW);
        for (int i = t; i < CH * 88; i += 256) {
            int ci = i / 88, lx = i % 88;
            int gx = ox0 + lx - 12;
            unsigned short v = 0;
            if (rowok && gx >= 0 && gx < HW) v = wb[ci * (HW * HW) + gy * HW + gx];
            sa[ky][ci][lx] = v;
        }
    }

    const int tco = t & 15, tpx = t >> 4;
    const int co0 = tco * 4, px0 = tpx * 4;
    float acc[4][4];
    #pragma unroll
    for (int i = 0; i < 4; ++i)
        #pragma unroll
        for (int j = 0; j < 4; ++j) acc[i][j] = 0.f;

    const unsigned short* wtu = (const unsigned short*)wt;
    for (int ky = 0; ky < 3; ++ky) {
        __syncthreads();   // previous compute done (iter>0) / sa staged (iter 0)
        for (int i = t; i < CH * 3 * 64; i += 256) swm[i] = wtu[ky * (CH * 3 * 64) + i];
        __syncthreads();

        for (int ci = 0; ci < CH; ++ci) {
            const unsigned short* arow = &sa[ky][ci][px0];
            const unsigned short* wrow = &swm[ci * 192 + co0];
            #pragma unroll
            for (int kx = 0; kx < 3; ++kx) {
                ushort4 av = *(const ushort4*)(arow + 12 * kx);
                ushort4 wv = *(const ushort4*)(wrow + 64 * kx);
                float a0 = b2f(av.x), a1 = b2f(av.y), a2 = b2f(av.z), a3 = b2f(av.w);
                float w0 = b2f(wv.x), w1 = b2f(wv.y), w2 = b2f(wv.z), w3 = b2f(wv.w);
                acc[0][0] = fmaf(w0, a0, acc[0][0]);
                acc[0][1] = fmaf(w0, a1, acc[0][1]);
                acc[0][2] = fmaf(w0, a2, acc[0][2]);
                acc[0][3] = fmaf(w0, a3, acc[0][3]);
                acc[1][0] = fmaf(w1, a0, acc[1][0]);
                acc[1][1] = fmaf(w1, a1, acc[1][1]);
                acc[1][2] = fmaf(w1, a2, acc[1][2]);
                acc[1][3] = fmaf(w1, a3, acc[1][3]);
                acc[2][0] = fmaf(w2, a0, acc[2][0]);
                acc[2][1] = fmaf(w2, a1, acc[2][1]);
                acc[2][2] = fmaf(w2, a2, acc[2][2]);
                acc[2][3] = fmaf(w2, a3, acc[2][3]);
                acc[3][0] = fmaf(w3, a0, acc[3][0]);
                acc[3][1] = fmaf(w3, a1, acc[3][1]);
                acc[3][2] = fmaf(w3, a2, acc[3][2]);
                acc[3][3] = fmaf(w3, a3, acc[3][3]);
            }
        }
    }

    #pragma unroll
    for (int i = 0; i < 4; ++i) {
        int co = co0 + i;
        float inv = sinv[co], bs = sbias[co];
        float4 r;
        r.x = fmaxf(fmaf(acc[i][0], inv, bs), 0.f);
        r.y = fmaxf(fmaf(acc[i][1], inv, bs), 0.f);
        r.z = fmaxf(fmaf(acc[i][2], inv, bs), 0.f);
        r.w = fmaxf(fmaf(acc[i][3], inv, bs), 0.f);
        *(float4*)&out[(size_t)(b * CH + co) * (HW * HW) + (size_t)oy * HW + ox0 + px0] = r;
    }
}

extern "C" void kernel_launch(void* const* d_in, const int* in_sizes, int n_in,
                              void* d_out, int out_size, void* d_ws, size_t ws_size,
                              hipStream_t stream) {
    const float* x     = (const float*)d_in[0];
    const float* ow    = (const float*)d_in[1];
    const float* ob    = (const float*)d_in[2];
    const float* cw    = (const float*)d_in[3];
    const float* gamma = (const float*)d_in[4];
    const float* beta  = (const float*)d_in[5];
    const float* mean  = (const float*)d_in[6];
    const float* var   = (const float*)d_in[7];
    float* out = (float*)d_out;

    __hip_bfloat16* warped = (__hip_bfloat16*)d_ws;                       // 64 MB
    __hip_bfloat16* wtb    = (__hip_bfloat16*)((char*)d_ws + (size_t)8 * CH * HW * HW * 2);

    wt_kernel<<<(64 * 64 * 9 + 255) / 256, 256, 0, stream>>>(cw, wtb);

    dim3 bA(16, 16);
    dim3 gA(16, 16, 8);
    offset_warp_kernel<<<gA, bA, 0, stream>>>(x, ow, ob, warped);

    conv_bn_relu_kernel<<<dim3(4, HW, 8), 256, 0, stream>>>(warped, wtb, gamma, beta, mean, var, out);
}

// Round 2
// 286.339 us; speedup vs baseline: 3.4523x; 3.4523x over previous
//
#include <hip/hip_runtime.h>
#include <hip/hip_bf16.h>
#include <cstdint>

#define HW 256
#define CH 64

typedef __attribute__((ext_vector_type(8))) short bf16x8;
typedef __attribute__((ext_vector_type(4))) float f32x4;

__device__ __forceinline__ float b2f(unsigned short u) {
    union { unsigned int i; float f; } c; c.i = ((unsigned int)u) << 16; return c.f;
}

__device__ __forceinline__ void gload16(const void* g, void* l) {
    __builtin_amdgcn_global_load_lds(
        (const __attribute__((address_space(1))) void*)g,
        (__attribute__((address_space(3))) void*)l, 16, 0, 0);
}

// ---------------------------------------------------------------------------
// Kernel W: conv_w [co][ci][ky][kx] f32 -> wt[ky][kx][co][ci] bf16, with
// 16B-chunk XOR swizzle within each co-row: chunk j stored at j ^ (co&7).
// ---------------------------------------------------------------------------
__global__ void wt_kernel(const float* __restrict__ cw, unsigned short* __restrict__ wt) {
    int i = blockIdx.x * 256 + threadIdx.x;
    if (i >= 9 * 64 * 64) return;
    int e = i & 7, j = (i >> 3) & 7, co = (i >> 6) & 63, t9 = i >> 12;
    int ky = t9 / 3, kx = t9 - ky * 3;
    int ci = j * 8 + e;
    float v = cw[co * 576 + ci * 9 + ky * 3 + kx];
    __hip_bfloat16 h = __float2bfloat16(v);
    wt[t9 * 4096 + co * 64 + ((j ^ (co & 7)) * 8) + e] = *(unsigned short*)&h;
}

// ---------------------------------------------------------------------------
// Kernel A: fused offset conv (fp32) + tanh + bilinear warp -> warped bf16
// NHWC layout [b][y][x][ci], 16B-chunk swizzle within pixel: chunk j at j^(x&7)
// block 16x16 threads = one 16x16 pixel tile; grid (16,16,B)
// ---------------------------------------------------------------------------
__global__ __launch_bounds__(256) void offset_warp_kernel(
    const float* __restrict__ x, const float* __restrict__ ow,
    const float* __restrict__ ob, unsigned short* __restrict__ warped)
{
    const int b = blockIdx.z;
    const int tx = threadIdx.x, ty = threadIdx.y;
    const int t = ty * 16 + tx;
    const int x0 = blockIdx.x * 16, y0 = blockIdx.y * 16;
    const int px = x0 + tx, py = y0 + ty;

    __shared__ float swt[2 * CH * 9];
    __shared__ float sxt[18][19];

    for (int i = t; i < 2 * CH * 9; i += 256) swt[i] = ow[i];

    float acc0 = ob[0], acc1 = ob[1];
    const float* xb = x + (size_t)b * CH * HW * HW;

    for (int ci = 0; ci < CH; ++ci) {
        __syncthreads();
        const float* xc = xb + (size_t)ci * HW * HW;
        for (int i = t; i < 18 * 18; i += 256) {
            int ly = i / 18, lx = i % 18;
            int gy = y0 + ly - 1, gx = x0 + lx - 1;
            float v = 0.f;
            if (gy >= 0 && gy < HW && gx >= 0 && gx < HW) v = xc[gy * HW + gx];
            sxt[ly][lx] = v;
        }
        __syncthreads();
        const float* w0 = &swt[ci * 9];
        const float* w1 = &swt[(CH + ci) * 9];
        #pragma unroll
        for (int ky = 0; ky < 3; ++ky)
            #pragma unroll
            for (int kx = 0; kx < 3; ++kx) {
                float v = sxt[ty + ky][tx + kx];
                acc0 = fmaf(v, w0[ky * 3 + kx], acc0);
                acc1 = fmaf(v, w1[ky * 3 + kx], acc1);
            }
    }

    float off0 = tanhf(acc0) * 2.0f;
    float off1 = tanhf(acc1) * 2.0f;
    float ix = fminf(fmaxf((float)px + off0, 0.f), (float)(HW - 1));
    float iy = fminf(fmaxf((float)py + off1, 0.f), (float)(HW - 1));
    float fx0 = floorf(ix), fy0 = floorf(iy);
    float wx = ix - fx0, wy = iy - fy0;
    int x0i = (int)fx0, y0i = (int)fy0;
    int x1i = min(x0i + 1, HW - 1), y1i = min(y0i + 1, HW - 1);
    float w00 = (1.f - wx) * (1.f - wy), w01 = wx * (1.f - wy);
    float w10 = (1.f - wx) * wy,         w11 = wx * wy;

    int i00 = y0i * HW + x0i, i01 = y0i * HW + x1i;
    int i10 = y1i * HW + x0i, i11 = y1i * HW + x1i;

    unsigned short* wb = warped + ((size_t)b * (HW * HW) + (size_t)py * HW + px) * CH;
    const int key = px & 7;
    #pragma unroll
    for (int j = 0; j < 8; ++j) {
        unsigned int pk[4];
        #pragma unroll
        for (int p = 0; p < 4; ++p) {
            int ci = j * 8 + p * 2;
            const float* xc0 = xb + (size_t)ci * (HW * HW);
            const float* xc1 = xb + (size_t)(ci + 1) * (HW * HW);
            float v0 = xc0[i00] * w00 + xc0[i01] * w01 + xc0[i10] * w10 + xc0[i11] * w11;
            float v1 = xc1[i00] * w00 + xc1[i01] * w01 + xc1[i10] * w10 + xc1[i11] * w11;
            __hip_bfloat16 h0 = __float2bfloat16(v0);
            __hip_bfloat16 h1 = __float2bfloat16(v1);
            pk[p] = (unsigned int)(*(unsigned short*)&h0) |
                    ((unsigned int)(*(unsigned short*)&h1) << 16);
        }
        uint4 q; q.x = pk[0]; q.y = pk[1]; q.z = pk[2]; q.w = pk[3];
        *(uint4*)&wb[(size_t)((j ^ key) * 8)] = q;
    }
}

// ---------------------------------------------------------------------------
// Kernel B: dilated(12) 3x3 conv 64->64 + BN + ReLU via bf16 MFMA implicit GEMM
// block = 256 threads (4 waves), computes 64co x 256px (one full output row).
// Wave w: 64co x 64px = 4x4 fragments of 16x16, K = 3ky x 3kx x 64ci.
// Act row staged per-ky via global_load_lds (linear dest, source pre-swizzled),
// weights per-ky likewise. All fragment reads are swizzled ds_read_b128.
// grid (256 oy, 8 b)
// ---------------------------------------------------------------------------
__global__ __launch_bounds__(256, 2) void conv_mfma_kernel(
    const unsigned short* __restrict__ warped, const unsigned short* __restrict__ wtb,
    const float* __restrict__ gamma, const float* __restrict__ beta,
    const float* __restrict__ mean, const float* __restrict__ var,
    float* __restrict__ out)
{
    __shared__ __align__(16) unsigned short sa[280 * 64];   // 35840 B act row (+12px halo each side)
    __shared__ __align__(16) unsigned short sw[3 * 64 * 64]; // 24576 B weights for one ky
    __shared__ float sinv[64], sbias[64];

    const int t = threadIdx.x;
    const int oy = blockIdx.x, b = blockIdx.y;
    const int wid = t >> 6, lane = t & 63;
    const int l15 = lane & 15, l4 = lane >> 4;

    if (t < 64) {
        float inv = gamma[t] * rsqrtf(var[t] + 1e-5f);
        sinv[t] = inv;
        sbias[t] = beta[t] - mean[t] * inv;
    }
    // zero the x-halo (stays zero across all ky: staging only overwrites [12,268))
    if (t < 192) {
        int p = t >> 3, sub = t & 7;
        int px = (p < 12) ? p : (256 + p);  // p 12..23 -> 268..279
        *(uint4*)&sa[px * 64 + sub * 8] = make_uint4(0, 0, 0, 0);
    }

    f32x4 acc[4][4];
    #pragma unroll
    for (int m = 0; m < 4; ++m)
        #pragma unroll
        for (int n = 0; n < 4; ++n) acc[m][n] = (f32x4){0.f, 0.f, 0.f, 0.f};

    const size_t bbase = (size_t)b * (HW * (size_t)HW * CH);

    for (int ky = 0; ky < 3; ++ky) {
        __syncthreads();   // prev compute / init done before overwriting LDS
        int gy = oy + (ky - 1) * 12;
        if (gy >= 0 && gy < HW) {
            const char* src = (const char*)(warped + bbase + (size_t)gy * (HW * CH));
            #pragma unroll
            for (int r = 0; r < 8; ++r)
                gload16(src + r * 4096 + t * 16,
                        (char*)sa + 1536 + r * 4096 + wid * 1024);
        } else {
            #pragma unroll
            for (int r = 0; r < 8; ++r)
                *(uint4*)((char*)sa + 1536 + r * 4096 + t * 16) = make_uint4(0, 0, 0, 0);
        }
        {
            const char* wsrc = (const char*)wtb + ky * 24576;
            #pragma unroll
            for (int r = 0; r < 6; ++r)
                gload16(wsrc + r * 4096 + t * 16,
                        (char*)sw + r * 4096 + wid * 1024);
        }
        asm volatile("s_waitcnt vmcnt(0)" ::: "memory");
        __syncthreads();

        #pragma unroll
        for (int kx = 0; kx < 3; ++kx) {
            #pragma unroll
            for (int ks = 0; ks < 2; ++ks) {
                const int jg = ks * 4 + l4;
                bf16x8 af[4], bfr[4];
                #pragma unroll
                for (int m = 0; m < 4; ++m) {
                    int co = m * 16 + l15;
                    int jp = jg ^ (co & 7);
                    af[m] = *(const bf16x8*)&sw[(kx * 64 + co) * 64 + jp * 8];
                }
                #pragma unroll
                for (int n = 0; n < 4; ++n) {
                    int pl = wid * 64 + n * 16 + l15 + kx * 12; // px_local in [0,280)
                    int c = jg ^ ((pl + 4) & 7);                // key = (pl-12)&7
                    bfr[n] = *(const bf16x8*)&sa[pl * 64 + c * 8];
                }
                #pragma unroll
                for (int m = 0; m < 4; ++m)
                    #pragma unroll
                    for (int n = 0; n < 4; ++n)
                        acc[m][n] = __builtin_amdgcn_mfma_f32_16x16x32_bf16(
                            af[m], bfr[n], acc[m][n], 0, 0, 0);
            }
        }
    }

    // epilogue: D layout col(px)=lane&15, row(co)=(lane>>4)*4+r
    #pragma unroll
    for (int m = 0; m < 4; ++m) {
        #pragma unroll
        for (int r = 0; r < 4; ++r) {
            int co = m * 16 + l4 * 4 + r;
            float inv = sinv[co], bs = sbias[co];
            float* orow = out + (((size_t)b * CH + co) * HW + oy) * HW + wid * 64 + l15;
            #pragma unroll
            for (int n = 0; n < 4; ++n)
                orow[n * 16] = fmaxf(fmaf(acc[m][n][r], inv, bs), 0.f);
        }
    }
}

extern "C" void kernel_launch(void* const* d_in, const int* in_sizes, int n_in,
                              void* d_out, int out_size, void* d_ws, size_t ws_size,
                              hipStream_t stream) {
    const float* x     = (const float*)d_in[0];
    const float* ow    = (const float*)d_in[1];
    const float* ob    = (const float*)d_in[2];
    const float* cw    = (const float*)d_in[3];
    const float* gamma = (const float*)d_in[4];
    const float* beta  = (const float*)d_in[5];
    const float* mean  = (const float*)d_in[6];
    const float* var   = (const float*)d_in[7];
    float* out = (float*)d_out;

    unsigned short* warped = (unsigned short*)d_ws;  // 64 MB NHWC bf16 (swizzled)
    unsigned short* wtb    = (unsigned short*)((char*)d_ws + (size_t)8 * CH * HW * HW * 2);

    wt_kernel<<<(9 * 64 * 64 + 255) / 256, 256, 0, stream>>>(cw, wtb);

    dim3 bA(16, 16);
    dim3 gA(16, 16, 8);
    offset_warp_kernel<<<gA, bA, 0, stream>>>(x, ow, ob, warped);

    conv_mfma_kernel<<<dim3(HW, 8), 256, 0, stream>>>(warped, wtb, gamma, beta, mean, var, out);
}